// Round 2
// baseline (181.691 us; speedup 1.0000x reference)
//
#include <hip/hip_runtime.h>
#include <hip/hip_bf16.h>

// TokenEncoder: B=8 L=2048 D=512 DM=1024 S=32 M=4 P=4096
// out = [tokens (8,2049,1024) f32][attn_keep (8,2049) as f32]

#define NB   8
#define NL   2048
#define ND   512
#define NDM  1024
#define NS   32
#define NTOK (NB * NL)         // 16384
#define LP1  (NL + 1)          // 2049
#define MAXTILES 160           // sum ceil(cnt_e/128) <= 16384/128 + 32

static __device__ __forceinline__ size_t attn_off() { return (size_t)NB * LP1 * NDM; }

typedef __attribute__((ext_vector_type(8))) short bf16x8;
typedef __attribute__((ext_vector_type(4))) float f32x4;

__device__ __forceinline__ unsigned short f2bf(float f) {
    unsigned int x = __float_as_uint(f);
    x += 0x7fffu + ((x >> 16) & 1u);   // RNE (inputs are finite)
    return (unsigned short)(x >> 16);
}

__device__ __forceinline__ bf16x8 cvt8(float4 a, float4 b) {
    bf16x8 r;
    r[0] = (short)f2bf(a.x); r[1] = (short)f2bf(a.y);
    r[2] = (short)f2bf(a.z); r[3] = (short)f2bf(a.w);
    r[4] = (short)f2bf(b.x); r[5] = (short)f2bf(b.y);
    r[6] = (short)f2bf(b.z); r[7] = (short)f2bf(b.w);
    return r;
}

__device__ __forceinline__ float4 ld4(const float* p) { return *(const float4*)p; }
__device__ __forceinline__ float4 add4(float4 a, float4 b) {
    return make_float4(a.x + b.x, a.y + b.y, a.z + b.z, a.w + b.w);
}

// ---- kernel 1a: count tokens per expert, write attn_keep ----
__global__ void k_count(const int* __restrict__ sid, const int* __restrict__ mask,
                        int* __restrict__ cnt, float* __restrict__ out) {
    int t = blockIdx.x * 256 + threadIdx.x;
    if (t >= NTOK) return;
    int s = sid[t];
    bool keep = mask[t] != 0;
    if (keep) atomicAdd(&cnt[s], 1);
    int b = t >> 11, l = t & (NL - 1);
    out[attn_off() + (size_t)b * LP1 + l + 1] = keep ? 1.0f : 0.0f;
    if (t < NB) out[attn_off() + (size_t)t * LP1] = 1.0f;   // CLS keep
}

// ---- kernel 1b: prefix sum + tile descriptors (serial, tiny) ----
__global__ void k_tiles(const int* __restrict__ cnt, int* __restrict__ meta,
                        int* __restrict__ cursor, int4* __restrict__ tiles) {
    if (threadIdx.x != 0) return;
    int start = 0, idx = 0;
    for (int e = 0; e < NS; ++e) {
        int c = cnt[e];
        cursor[e] = start;
        for (int r = 0; r < c; r += 128) {
            tiles[idx++] = make_int4(e, start + r, min(128, c - r), 0);
        }
        start += c;
    }
    meta[0] = idx;
}

// ---- kernel 1c: scatter token ids into expert-grouped list ----
__global__ void k_place(const int* __restrict__ sid, const int* __restrict__ mask,
                        int* __restrict__ cursor, int* __restrict__ tokList) {
    int t = blockIdx.x * 256 + threadIdx.x;
    if (t >= NTOK) return;
    if (mask[t] != 0) {
        int p = atomicAdd(&cursor[sid[t]], 1);
        tokList[p] = t;
    }
}

// ---- kernel 2: embedding sums for ALL rows (CLS / padded / unpadded) ----
__global__ void k_embed(const int* __restrict__ pos, const int* __restrict__ sid,
                        const int* __restrict__ mod, const int* __restrict__ role,
                        const int* __restrict__ mask,
                        const float* __restrict__ b_proj, const float* __restrict__ cls_c,
                        const float* __restrict__ pos_e, const float* __restrict__ id_e,
                        const float* __restrict__ mod_e, const float* __restrict__ role_e,
                        float* __restrict__ out) {
    int l1 = blockIdx.x;            // 0..2048
    int b  = blockIdx.y;            // 0..7
    int o  = threadIdx.x * 4;       // 256 threads * 4 = 1024
    float4 v;
    if (l1 == 0) {
        v = add4(add4(ld4(cls_c + o), ld4(pos_e + o)), ld4(id_e + (size_t)NS * NDM + o));
    } else {
        int t = b * NL + l1 - 1;
        int p = pos[t], s = sid[t], m = mod[t], r = role[t];
        v = add4(ld4(pos_e + (size_t)p * NDM + o), ld4(id_e + (size_t)s * NDM + o));
        v = add4(v, add4(ld4(mod_e + (size_t)m * NDM + o), ld4(role_e + (size_t)r * NDM + o)));
        if (mask[t] != 0) v = add4(v, ld4(b_proj + (size_t)s * NDM + o));
    }
    *(float4*)&out[((size_t)b * LP1 + l1) * NDM + o] = v;
}

// ---- kernel 3: grouped GEMM, C[token, o] += emb[token,:] . W[e][o,:] ----
__global__ __launch_bounds__(256) void k_gemm(
    const float* __restrict__ emb, const float* __restrict__ Wp,
    const int* __restrict__ tokList, const int4* __restrict__ tiles,
    const int* __restrict__ meta, float* __restrict__ out) {
    if (blockIdx.x >= meta[0]) return;
    int4 td = tiles[blockIdx.x];
    const int e = td.x, gRow = td.y, nRows = td.z;
    const int nBase = blockIdx.y * 128;

    __shared__ short aT[128][40];   // 40-short stride: 16B-aligned rows, 2-way banks (free)
    __shared__ short bT[128][40];

    const int tid  = threadIdx.x;
    const int lane = tid & 63;
    const int wv   = tid >> 6;
    const int wr   = wv >> 1, wc = wv & 1;   // 2x2 waves, 64x64 each

    // staging: 2 threads per row, 16 floats each
    const int sRow  = tid >> 1;
    const int sHalf = tid & 1;
    const int tIdx  = (sRow < nRows) ? sRow : 0;
    const int stok  = tokList[gRow + tIdx];
    const float* aSrc = emb + (size_t)stok * ND + sHalf * 16;
    const float* bSrc = Wp + ((size_t)e * NDM + nBase + sRow) * ND + sHalf * 16;

    f32x4 acc[4][4];
#pragma unroll
    for (int i = 0; i < 4; ++i)
#pragma unroll
        for (int j = 0; j < 4; ++j)
            acc[i][j] = (f32x4){0.f, 0.f, 0.f, 0.f};

    const int kGrp = (lane >> 4) * 8;   // k offset of this lane's fragment
    const int fr   = lane & 15;         // row (A) / col (B) within fragment

    for (int ks = 0; ks < ND / 32; ++ks) {
        const float4* ap = (const float4*)(aSrc + ks * 32);
        const float4* bp = (const float4*)(bSrc + ks * 32);
        float4 a0 = ap[0], a1 = ap[1], a2 = ap[2], a3 = ap[3];
        float4 b0 = bp[0], b1 = bp[1], b2 = bp[2], b3 = bp[3];
        __syncthreads();
        *(bf16x8*)&aT[sRow][sHalf * 16]     = cvt8(a0, a1);
        *(bf16x8*)&aT[sRow][sHalf * 16 + 8] = cvt8(a2, a3);
        *(bf16x8*)&bT[sRow][sHalf * 16]     = cvt8(b0, b1);
        *(bf16x8*)&bT[sRow][sHalf * 16 + 8] = cvt8(b2, b3);
        __syncthreads();
        bf16x8 af[4], bf[4];
#pragma unroll
        for (int i = 0; i < 4; ++i) af[i] = *(const bf16x8*)&aT[wr * 64 + i * 16 + fr][kGrp];
#pragma unroll
        for (int j = 0; j < 4; ++j) bf[j] = *(const bf16x8*)&bT[wc * 64 + j * 16 + fr][kGrp];
#pragma unroll
        for (int i = 0; i < 4; ++i)
#pragma unroll
            for (int j = 0; j < 4; ++j)
                acc[i][j] = __builtin_amdgcn_mfma_f32_16x16x32_bf16(af[i], bf[j], acc[i][j], 0, 0, 0);
    }

    // epilogue: out[tokenRow, col] += acc   (k_embed already wrote embedding sums)
    const int rQ = (lane >> 4) * 4;
#pragma unroll
    for (int i = 0; i < 4; ++i) {
#pragma unroll
        for (int r = 0; r < 4; ++r) {
            int row = wr * 64 + i * 16 + rQ + r;
            if (row < nRows) {
                int t = tokList[gRow + row];
                size_t orow = ((size_t)(t >> 11) * LP1 + (t & (NL - 1)) + 1) * NDM;
#pragma unroll
                for (int j = 0; j < 4; ++j) {
                    size_t off = orow + nBase + wc * 64 + j * 16 + fr;
                    out[off] += acc[i][j][r];
                }
            }
        }
    }
}

extern "C" void kernel_launch(void* const* d_in, const int* in_sizes, int n_in,
                              void* d_out, int out_size, void* d_ws, size_t ws_size,
                              hipStream_t stream) {
    const float* emb  = (const float*)d_in[0];
    const int* pos    = (const int*)d_in[1];
    const int* sid    = (const int*)d_in[2];
    const int* mod    = (const int*)d_in[3];
    const int* role   = (const int*)d_in[4];
    const int* mask   = (const int*)d_in[5];   // np.bool_ pushed as int32
    const float* Wp   = (const float*)d_in[6];
    const float* bp   = (const float*)d_in[7];
    const float* cls  = (const float*)d_in[8];
    const float* pe   = (const float*)d_in[9];
    const float* ie   = (const float*)d_in[10];
    const float* me   = (const float*)d_in[11];
    const float* re   = (const float*)d_in[12];
    float* out = (float*)d_out;

    int* ws       = (int*)d_ws;
    int* cnt      = ws;               // 32 ints
    int* meta     = ws + 32;          // 1 int (tileCount)
    int* cursor   = ws + 64;          // 32 ints
    int4* tiles   = (int4*)(ws + 128); // MAXTILES * int4 (byte off 512, aligned)
    int* tokList  = ws + 1024;        // 16384 ints

    hipMemsetAsync(cnt, 0, 32 * sizeof(int), stream);
    k_count<<<NTOK / 256, 256, 0, stream>>>(sid, mask, cnt, out);
    k_tiles<<<1, 64, 0, stream>>>(cnt, meta, cursor, tiles);
    k_place<<<NTOK / 256, 256, 0, stream>>>(sid, mask, cursor, tokList);

    dim3 ge(LP1, NB);
    k_embed<<<ge, 256, 0, stream>>>(pos, sid, mod, role, mask, bp, cls, pe, ie, me, re, out);

    dim3 gg(MAXTILES, NDM / 128);
    k_gemm<<<gg, 256, 0, stream>>>(emb, Wp, tokList, tiles, meta, out);
}